// Round 6
// baseline (420.632 us; speedup 1.0000x reference)
//
#include <hip/hip_runtime.h>
#include <math.h>

#define N_NODES 50000
#define N_EDGES 800000
#define DIN 256
#define DHID 128
#define DOUT 64
// Padded CSR row stride. In-degree ~ Poisson(16); P(deg > 64) ~ 1e-19 -> safe.
#define CSTRIDE 64
#define ZROW N_NODES            // sentinel row (kept zero) for pad entries
#define HBLOCKS 256
#define HCHUNK (N_EDGES / HBLOCKS)     // 3125 exactly
#define HWORDS (N_NODES / 4)           // 12500 packed byte-counters per block
#define SLICE ((size_t)(N_NODES + 1) * 16)   // floats per 16-col slice

// ---------------- CSR build: histogram / prefix / LDS-atomic fill ----------------

// byte-packed LDS-privatized histogram (4 bins per u32). Per-block per-node
// counts <= total degree (~45-64) << 255 -> no byte carry.
__global__ void k_hist(const int* __restrict__ idx, unsigned int* __restrict__ partials) {
    __shared__ unsigned int h[HWORDS];
    int t = threadIdx.x;
    for (int w = t; w < HWORDS; w += 256) h[w] = 0u;
    __syncthreads();
    int base = blockIdx.x * HCHUNK;
    for (int i = t; i < HCHUNK; i += 256) {
        int s = idx[base + i];
        atomicAdd(&h[s >> 2], 1u << ((s & 3) << 3));
    }
    __syncthreads();
    unsigned int* outp = partials + (size_t)blockIdx.x * HWORDS;
    for (int w = t; w < HWORDS; w += 256) outp[w] = h[w];
}

// merged: deg_out = sum(pS) ; prefix/deg_in = scan(pD) ; norms ns/nd/cc.
// One thread owns 4 nodes (one packed word column).
__global__ void k_hpre(const unsigned int* __restrict__ pS,
                       const unsigned int* __restrict__ pD,
                       unsigned int* __restrict__ prefix,
                       int* __restrict__ deg_in,
                       float* __restrict__ ns, float* __restrict__ nd,
                       float* __restrict__ cc) {
    int wid = blockIdx.x * 256 + threadIdx.x;
    if (wid >= HWORDS) return;
    unsigned int o0 = 0, o1 = 0, o2 = 0, o3 = 0;
#pragma unroll 4
    for (int b = 0; b < HBLOCKS; ++b) {
        unsigned int w = pS[(size_t)b * HWORDS + wid];
        o0 += w & 0xffu; o1 += (w >> 8) & 0xffu;
        o2 += (w >> 16) & 0xffu; o3 += w >> 24;
    }
    unsigned int run = 0;
    for (int b = 0; b < HBLOCKS; ++b) {
        unsigned int w = pD[(size_t)b * HWORDS + wid];
        prefix[(size_t)b * HWORDS + wid] = run;
        run += w;                        // packed per-byte add, no carry
    }
    unsigned int i0 = run & 0xffu, i1 = (run >> 8) & 0xffu;
    unsigned int i2 = (run >> 16) & 0xffu, i3 = run >> 24;
    int4 di; di.x = (int)i0; di.y = (int)i1; di.z = (int)i2; di.w = (int)i3;
    *(int4*)(deg_in + (wid << 2)) = di;

    unsigned int dov[4] = {o0, o1, o2, o3};
    unsigned int div_[4] = {i0, i1, i2, i3};
    float4 vns, vnd, vcc;
    float* pns = &vns.x; float* pnd = &vnd.x; float* pcc = &vcc.x;
#pragma unroll
    for (int q = 0; q < 4; ++q) {
        unsigned int a = dov[q] < 1u ? 1u : dov[q];
        unsigned int b = div_[q] < 1u ? 1u : div_[q];
        float fa = 1.0f / sqrtf((float)a);
        float fb = 1.0f / sqrtf((float)b);
        pns[q] = fa; pnd[q] = fb; pcc[q] = fa * fb;
    }
    *(float4*)(ns + (wid << 2)) = vns;
    *(float4*)(nd + (wid << 2)) = vnd;
    *(float4*)(cc + (wid << 2)) = vcc;
}

// sentinel-pad each row to a multiple of 8. Pads write slots [deg, pad8) which
// are disjoint from k_fill's slots [0, deg) -> order independent.
__global__ void k_pad(unsigned short* __restrict__ csr, const int* __restrict__ deg_in) {
    int node = blockIdx.x * 256 + threadIdx.x;
    if (node >= N_NODES) return;
    int d = deg_in[node];
    int npad = (d + 7) & ~7;
    for (int p = d; p < npad; ++p) csr[(node << 6) + p] = (unsigned short)ZROW;
}

// fill csr using LDS atomics only: LDS starts at this block's packed prefix,
// atomicAdd returns the exact slot. Zero global atomics.
__global__ void k_fill(const int* __restrict__ src, const int* __restrict__ dst,
                       const unsigned int* __restrict__ prefix,
                       unsigned short* __restrict__ csr) {
    __shared__ unsigned int h[HWORDS];
    int t = threadIdx.x;
    const unsigned int* prow = prefix + (size_t)blockIdx.x * HWORDS;
    for (int w = t; w < HWORDS; w += 256) h[w] = prow[w];
    __syncthreads();
    int base = blockIdx.x * HCHUNK;
    for (int i = t; i < HCHUNK; i += 256) {
        int s = src[base + i], d = dst[base + i];
        int sh = (d & 3) << 3;
        unsigned int old = atomicAdd(&h[d >> 2], 1u << sh);
        int slot = (int)((old >> sh) & 0xffu);
        csr[(d << 6) + slot] = (unsigned short)s;
    }
}

// ---------------- weight folding + sentinel-row zeroing ----------------
// blocks 0..63: W13 = W1@W3 ; block 64: bb = b1@W3 ; block 65: zero ZROW rows
// in all 4 slices of both ping-pong feature buffers.

__global__ void k_weights(const float* __restrict__ W1, const float* __restrict__ b1,
                          const float* __restrict__ W3,
                          float* __restrict__ W13, float* __restrict__ bb,
                          float* __restrict__ Y0, float* __restrict__ Y1) {
    if (blockIdx.x == 65) {
        int t = threadIdx.x;
        if (t < 64) {
            int qq = t >> 4, c2 = t & 15;
            Y0[(size_t)qq * SLICE + ((size_t)ZROW << 4) + c2] = 0.f;
            Y1[(size_t)qq * SLICE + ((size_t)ZROW << 4) + c2] = 0.f;
        }
        return;
    }
    if (blockIdx.x == 64) {
        int j = threadIdx.x;
        if (j < DOUT) {
            float s = 0.f;
            for (int k = 0; k < DHID; ++k) s += b1[k] * W3[k * DOUT + j];
            bb[j] = s;
        }
        return;
    }
    int idx = blockIdx.x * 256 + threadIdx.x;  // 16384 outputs
    int i = idx >> 6, j = idx & 63;
    float s = 0.f;
    for (int k = 0; k < DHID; ++k) s += W1[i * DHID + k] * W3[k * DOUT + j];
    W13[idx] = s;
}

// ---------------- dense GEMM: Y = ns ∘ (X @ W13), written COLUMN-SLICED ----------------

__global__ void k_gemm(const float* __restrict__ X, const float* __restrict__ W13,
                       const float* __restrict__ ns, float* __restrict__ Y) {
    __shared__ float As[16][68];   // [k][row], padded
    __shared__ float Bs[16][64];   // [k][col]
    int tid = threadIdx.x;
    int tx = tid & 15, ty = tid >> 4;
    int row0 = blockIdx.x * 64;
    float acc[4][4];
#pragma unroll
    for (int i = 0; i < 4; ++i)
#pragma unroll
        for (int j = 0; j < 4; ++j) acc[i][j] = 0.f;

    int lr = tid >> 2;            // 0..63 row within tile
    int lk = (tid & 3) << 2;      // 0,4,8,12
    int arow = row0 + lr;
    if (arow > N_NODES - 1) arow = N_NODES - 1;   // clamp: garbage rows never stored

    for (int k0 = 0; k0 < DIN; k0 += 16) {
        float4 a = *(const float4*)(X + (size_t)arow * DIN + k0 + lk);
        As[lk + 0][lr] = a.x; As[lk + 1][lr] = a.y;
        As[lk + 2][lr] = a.z; As[lk + 3][lr] = a.w;
        float4 b = *(const float4*)(W13 + (size_t)(k0 + (tid >> 4)) * DOUT + ((tid & 15) << 2));
        *(float4*)&Bs[tid >> 4][(tid & 15) << 2] = b;
        __syncthreads();
#pragma unroll
        for (int k = 0; k < 16; ++k) {
            float4 av = *(const float4*)&As[k][ty << 2];
            float4 bv = *(const float4*)&Bs[k][tx << 2];
            float ar[4] = {av.x, av.y, av.z, av.w};
            float br[4] = {bv.x, bv.y, bv.z, bv.w};
#pragma unroll
            for (int i = 0; i < 4; ++i)
#pragma unroll
                for (int j = 0; j < 4; ++j) acc[i][j] += ar[i] * br[j];
        }
        __syncthreads();
    }
    int qq = tx >> 2;             // column quarter
    int co = (tx & 3) << 2;       // offset within the 16-col slice
#pragma unroll
    for (int i = 0; i < 4; ++i) {
        int row = row0 + (ty << 2) + i;
        if (row < N_NODES) {
            float nsr = ns[row];
            float4 o;
            o.x = acc[i][0] * nsr; o.y = acc[i][1] * nsr;
            o.z = acc[i][2] * nsr; o.w = acc[i][3] * nsr;
            *(float4*)(Y + (size_t)qq * SLICE + ((size_t)row << 4) + co) = o;
        }
    }
}

// ---------------- XCD-sliced pull SpMM ----------------
// Features stored as 4 column-slices of (N+1)x16 floats (3.2 MB each — fits a
// 4 MB XCD L2). Quarter q is processed only by blocks with blockIdx%8 in
// {2q,2q+1} (XCD round-robin heuristic): each XCD's gathers stay inside its
// L2-resident slice. Wave = 16 cols x 4 edge-slots -> 4 edges per 64 B-row
// gather instruction; npad-bucketed unrolled paths keep 2-8 gathers in flight.
// MODE 0: y = cc*acc + ns*bb[col] ; MODE 1: y = cc*acc ; MODE 2 (row-major out):
// y = nd*acc + b3[col].

template <int MODE>
__global__ void k_spmm(const float* __restrict__ xs, float* __restrict__ ys,
                       const unsigned short* __restrict__ csr,
                       const int* __restrict__ cnt,
                       const float* __restrict__ cc, const float* __restrict__ ns,
                       const float* __restrict__ nd,
                       const float* __restrict__ bb, const float* __restrict__ b3) {
    int xcd  = blockIdx.x & 7;
    int q    = xcd >> 1;
    int half = xcd & 1;
    int task = (blockIdx.x >> 3) * 4 + (threadIdx.x >> 6);  // 0..24999
    int node = task * 2 + half;
    int lane = threadIdx.x & 63;
    int e = lane >> 4, c = lane & 15;
    int sv = csr[(node << 6) + lane];      // whole padded row, one 128B load
    int npad = (cnt[node] + 7) & ~7;
    const float* xq = xs + (size_t)q * SLICE + c;
    float a0 = 0.f, a1 = 0.f, a2 = 0.f, a3 = 0.f;
#define G(OFF, ACC) do { int s_ = __shfl(sv, (OFF) + e); ACC += xq[(size_t)s_ << 4]; } while (0)
    if (npad == 16) {
        G(0, a0); G(4, a1); G(8, a2); G(12, a3);
    } else if (npad == 24) {
        G(0, a0); G(4, a1); G(8, a2); G(12, a3); G(16, a0); G(20, a1);
    } else if (npad == 8) {
        G(0, a0); G(4, a1);
    } else if (npad == 32) {
        G(0, a0); G(4, a1); G(8, a2); G(12, a3);
        G(16, a0); G(20, a1); G(24, a2); G(28, a3);
    } else {
        for (int j = 0; j < npad; j += 8) { G(j, a0); G(j + 4, a1); }
    }
#undef G
    float acc = (a0 + a1) + (a2 + a3);
    acc += __shfl_xor(acc, 16);
    acc += __shfl_xor(acc, 32);

    int col = (q << 4) + c;
    float r;
    if (MODE == 0)      r = cc[node] * acc + ns[node] * bb[col];
    else if (MODE == 1) r = cc[node] * acc;
    else                r = nd[node] * acc + b3[col];
    if (lane < 16) {
        if (MODE == 2) ys[((size_t)node << 6) + col] = r;
        else           ys[(size_t)q * SLICE + ((size_t)node << 4) + c] = r;
    }
}

// ---------------- launcher ----------------

extern "C" void kernel_launch(void* const* d_in, const int* in_sizes, int n_in,
                              void* d_out, int out_size, void* d_ws, size_t ws_size,
                              hipStream_t stream) {
    const float* X   = (const float*)d_in[0];
    const int*   src = (const int*)d_in[1];
    const int*   dst = (const int*)d_in[2];
    const float* W1  = (const float*)d_in[3];
    const float* b1  = (const float*)d_in[4];
    const float* W3  = (const float*)d_in[5];
    const float* b3  = (const float*)d_in[6];
    float* out = (float*)d_out;

    char* ws = (char*)d_ws;
    size_t off = 0;
    auto alloc = [&](size_t bytes) -> void* {
        void* p = ws + off;
        off = (off + bytes + 255) & ~(size_t)255;
        return p;
    };
    // big buffers, time-multiplexed (stream order guarantees safety):
    //   bufA: partialsS (hist src) -> prefix -> Y1 (sliced)
    //   bufB: partialsD (hist dst) -> Y0 (sliced)
    const size_t BIGSZ = SLICE * 4 * 4;   // 12.8 MB >= HBLOCKS*HWORDS*4
    char* bufA = (char*)alloc(BIGSZ);
    char* bufB = (char*)alloc(BIGSZ);
    int*            deg_in  = (int*)alloc((size_t)N_NODES * 4);
    unsigned short* csr     = (unsigned short*)alloc((size_t)N_NODES * CSTRIDE * 2);
    float*          ns      = (float*)alloc((size_t)N_NODES * 4);
    float*          nd      = (float*)alloc((size_t)N_NODES * 4);
    float*          cc      = (float*)alloc((size_t)N_NODES * 4);
    float*          W13     = (float*)alloc((size_t)DIN * DOUT * 4);
    float*          bb      = (float*)alloc(DOUT * 4);

    unsigned int* pS   = (unsigned int*)bufA;   // src partial histograms
    unsigned int* pD   = (unsigned int*)bufB;   // dst partial histograms
    unsigned int* pref = (unsigned int*)bufA;   // per-(block,node) packed offsets
    float*        Y0   = (float*)bufB;          // sliced features, ping
    float*        Y1   = (float*)bufA;          // sliced features, pong

    const int nblk = (N_NODES + 255) / 256;   // 196
    const int hblk = (HWORDS + 255) / 256;    // 49
    const int sblk = (N_NODES / 8) * 8;       // 50000 blocks: 8-XCD x 6250

    k_hist<<<HBLOCKS, 256, 0, stream>>>(src, pS);
    k_hist<<<HBLOCKS, 256, 0, stream>>>(dst, pD);
    k_hpre<<<hblk, 256, 0, stream>>>(pS, pD, pref, deg_in, ns, nd, cc);
    k_pad<<<nblk, 256, 0, stream>>>(csr, deg_in);              // disjoint slots vs fill
    k_fill<<<HBLOCKS, 256, 0, stream>>>(src, dst, pref, csr);  // pref dead after

    k_weights<<<66, 256, 0, stream>>>(W1, b1, W3, W13, bb, Y0, Y1);

    // Y0 = ns ∘ (X @ (W1@W3)), column-sliced
    k_gemm<<<(N_NODES + 63) / 64, 256, 0, stream>>>(X, W13, ns, Y0);

    // 6 propagation passes; bias bb injected in pass 1, b3 in pass 6
    k_spmm<0><<<sblk, 256, 0, stream>>>(Y0, Y1, csr, deg_in, cc, ns, nd, bb, b3);
    k_spmm<1><<<sblk, 256, 0, stream>>>(Y1, Y0, csr, deg_in, cc, ns, nd, bb, b3);
    k_spmm<1><<<sblk, 256, 0, stream>>>(Y0, Y1, csr, deg_in, cc, ns, nd, bb, b3);
    k_spmm<1><<<sblk, 256, 0, stream>>>(Y1, Y0, csr, deg_in, cc, ns, nd, bb, b3);
    k_spmm<1><<<sblk, 256, 0, stream>>>(Y0, Y1, csr, deg_in, cc, ns, nd, bb, b3);
    k_spmm<2><<<sblk, 256, 0, stream>>>(Y1, out, csr, deg_in, cc, ns, nd, bb, b3);
}

// Round 7
// 326.204 us; speedup vs baseline: 1.2895x; 1.2895x over previous
//
#include <hip/hip_runtime.h>
#include <math.h>

#define N_NODES 50000
#define N_EDGES 800000
#define DIN 256
#define DHID 128
#define DOUT 64
// Padded CSR row stride. In-degree ~ Poisson(16); P(deg > 64) ~ 1e-19 -> safe.
#define CSTRIDE 64
#define ZROW N_NODES            // sentinel row (kept zero)
#define HBLOCKS 256
#define HCHUNK (N_EDGES / HBLOCKS)     // 3125 exactly
#define HWORDS (N_NODES / 4)           // 12500 packed byte-counters per block
#define SLICE ((size_t)(N_NODES + 1) * 16)   // floats per 16-col slice
#define NGROUPS (N_NODES / 4)          // 12500 4-node groups

// ---------------- CSR build ----------------

// pre-fill every csr slot with the sentinel (k_fill overwrites [0,deg)).
__global__ void k_sent(unsigned int* __restrict__ csr32) {
    int i = blockIdx.x * 256 + threadIdx.x;          // 800000 uint2 writes
    unsigned int v = (unsigned int)ZROW | ((unsigned int)ZROW << 16);
    uint2 o; o.x = v; o.y = v;
    ((uint2*)csr32)[i] = o;
}

// byte-packed LDS-privatized histogram (4 bins per u32).
__global__ void k_hist(const int* __restrict__ idx, unsigned int* __restrict__ partials) {
    __shared__ unsigned int h[HWORDS];
    int t = threadIdx.x;
    for (int w = t; w < HWORDS; w += 256) h[w] = 0u;
    __syncthreads();
    int base = blockIdx.x * HCHUNK;
    for (int i = t; i < HCHUNK; i += 256) {
        int s = idx[base + i];
        atomicAdd(&h[s >> 2], 1u << ((s & 3) << 3));
    }
    __syncthreads();
    unsigned int* outp = partials + (size_t)blockIdx.x * HWORDS;
    for (int w = t; w < HWORDS; w += 256) outp[w] = h[w];
}

// merged: deg_out = sum(pS) ; prefix/deg_in = scan(pD) ; norms ns/nd/cc.
__global__ void k_hpre(const unsigned int* __restrict__ pS,
                       const unsigned int* __restrict__ pD,
                       unsigned int* __restrict__ prefix,
                       int* __restrict__ deg_in,
                       float* __restrict__ ns, float* __restrict__ nd,
                       float* __restrict__ cc) {
    int wid = blockIdx.x * 256 + threadIdx.x;
    if (wid >= HWORDS) return;
    unsigned int o0 = 0, o1 = 0, o2 = 0, o3 = 0;
#pragma unroll 4
    for (int b = 0; b < HBLOCKS; ++b) {
        unsigned int w = pS[(size_t)b * HWORDS + wid];
        o0 += w & 0xffu; o1 += (w >> 8) & 0xffu;
        o2 += (w >> 16) & 0xffu; o3 += w >> 24;
    }
    unsigned int run = 0;
    for (int b = 0; b < HBLOCKS; ++b) {
        unsigned int w = pD[(size_t)b * HWORDS + wid];
        prefix[(size_t)b * HWORDS + wid] = run;
        run += w;                        // packed per-byte add, no carry (deg<=64)
    }
    unsigned int i0 = run & 0xffu, i1 = (run >> 8) & 0xffu;
    unsigned int i2 = (run >> 16) & 0xffu, i3 = run >> 24;
    int4 di; di.x = (int)i0; di.y = (int)i1; di.z = (int)i2; di.w = (int)i3;
    *(int4*)(deg_in + (wid << 2)) = di;

    unsigned int dov[4] = {o0, o1, o2, o3};
    unsigned int div_[4] = {i0, i1, i2, i3};
    float4 vns, vnd, vcc;
    float* pns = &vns.x; float* pnd = &vnd.x; float* pcc = &vcc.x;
#pragma unroll
    for (int q = 0; q < 4; ++q) {
        unsigned int a = dov[q] < 1u ? 1u : dov[q];
        unsigned int b = div_[q] < 1u ? 1u : div_[q];
        float fa = 1.0f / sqrtf((float)a);
        float fb = 1.0f / sqrtf((float)b);
        pns[q] = fa; pnd[q] = fb; pcc[q] = fa * fb;
    }
    *(float4*)(ns + (wid << 2)) = vns;
    *(float4*)(nd + (wid << 2)) = vnd;
    *(float4*)(cc + (wid << 2)) = vcc;
}

// fill csr using LDS atomics only (zero global atomics).
__global__ void k_fill(const int* __restrict__ src, const int* __restrict__ dst,
                       const unsigned int* __restrict__ prefix,
                       unsigned short* __restrict__ csr) {
    __shared__ unsigned int h[HWORDS];
    int t = threadIdx.x;
    const unsigned int* prow = prefix + (size_t)blockIdx.x * HWORDS;
    for (int w = t; w < HWORDS; w += 256) h[w] = prow[w];
    __syncthreads();
    int base = blockIdx.x * HCHUNK;
    for (int i = t; i < HCHUNK; i += 256) {
        int s = src[base + i], d = dst[base + i];
        int sh = (d & 3) << 3;
        unsigned int old = atomicAdd(&h[d >> 2], 1u << sh);
        int slot = (int)((old >> sh) & 0xffu);
        csr[(d << 6) + slot] = (unsigned short)s;
    }
}

// ---------------- weight folding + sentinel-row zeroing ----------------

__global__ void k_weights(const float* __restrict__ W1, const float* __restrict__ b1,
                          const float* __restrict__ W3,
                          float* __restrict__ W13, float* __restrict__ bb,
                          float* __restrict__ Y0, float* __restrict__ Y1) {
    if (blockIdx.x == 65) {
        int t = threadIdx.x;
        if (t < 64) {
            int qq = t >> 4, c2 = t & 15;
            Y0[(size_t)qq * SLICE + ((size_t)ZROW << 4) + c2] = 0.f;
            Y1[(size_t)qq * SLICE + ((size_t)ZROW << 4) + c2] = 0.f;
        }
        return;
    }
    if (blockIdx.x == 64) {
        int j = threadIdx.x;
        if (j < DOUT) {
            float s = 0.f;
            for (int k = 0; k < DHID; ++k) s += b1[k] * W3[k * DOUT + j];
            bb[j] = s;
        }
        return;
    }
    int idx = blockIdx.x * 256 + threadIdx.x;
    int i = idx >> 6, j = idx & 63;
    float s = 0.f;
    for (int k = 0; k < DHID; ++k) s += W1[i * DHID + k] * W3[k * DOUT + j];
    W13[idx] = s;
}

// ---------------- dense GEMM: Y = ns ∘ (X @ W13), written COLUMN-SLICED ----------------

__global__ void k_gemm(const float* __restrict__ X, const float* __restrict__ W13,
                       const float* __restrict__ ns, float* __restrict__ Y) {
    __shared__ float As[16][68];
    __shared__ float Bs[16][64];
    int tid = threadIdx.x;
    int tx = tid & 15, ty = tid >> 4;
    int row0 = blockIdx.x * 64;
    float acc[4][4];
#pragma unroll
    for (int i = 0; i < 4; ++i)
#pragma unroll
        for (int j = 0; j < 4; ++j) acc[i][j] = 0.f;

    int lr = tid >> 2;
    int lk = (tid & 3) << 2;
    int arow = row0 + lr;
    if (arow > N_NODES - 1) arow = N_NODES - 1;

    for (int k0 = 0; k0 < DIN; k0 += 16) {
        float4 a = *(const float4*)(X + (size_t)arow * DIN + k0 + lk);
        As[lk + 0][lr] = a.x; As[lk + 1][lr] = a.y;
        As[lk + 2][lr] = a.z; As[lk + 3][lr] = a.w;
        float4 b = *(const float4*)(W13 + (size_t)(k0 + (tid >> 4)) * DOUT + ((tid & 15) << 2));
        *(float4*)&Bs[tid >> 4][(tid & 15) << 2] = b;
        __syncthreads();
#pragma unroll
        for (int k = 0; k < 16; ++k) {
            float4 av = *(const float4*)&As[k][ty << 2];
            float4 bv = *(const float4*)&Bs[k][tx << 2];
            float ar[4] = {av.x, av.y, av.z, av.w};
            float br[4] = {bv.x, bv.y, bv.z, bv.w};
#pragma unroll
            for (int i = 0; i < 4; ++i)
#pragma unroll
                for (int j = 0; j < 4; ++j) acc[i][j] += ar[i] * br[j];
        }
        __syncthreads();
    }
    int qq = tx >> 2;
    int co = (tx & 3) << 2;
#pragma unroll
    for (int i = 0; i < 4; ++i) {
        int row = row0 + (ty << 2) + i;
        if (row < N_NODES) {
            float nsr = ns[row];
            float4 o;
            o.x = acc[i][0] * nsr; o.y = acc[i][1] * nsr;
            o.z = acc[i][2] * nsr; o.w = acc[i][3] * nsr;
            *(float4*)(Y + (size_t)qq * SLICE + ((size_t)row << 4) + co) = o;
        }
    }
}

// ---------------- sliced pull SpMM: 4 nodes x 4 edge-slots x float4 per wave ------------
// Wave lane = (n<<4) | (e<<2) | c4 : node-slot n, edge-slot e, column-quad c4.
// csr rows staged in LDS once per wave; loop does ds_read_u16 (lane-constant addr
// + immediate offset -> broadcast, no dynamic shuffles) + one dwordx4 gather per
// 16 edge-visits. Loop bound = max degree of the 4 nodes (scalar pipe); sentinel
// entries gather the zeroed ZROW row.
// MODE 0: y = cc*acc + ns*bb[col]; MODE 1: y = cc*acc; MODE 2: y = nd*acc + b3[col].

template <int MODE>
__launch_bounds__(256, 8)
__global__ void k_spmm(const float* __restrict__ xs, float* __restrict__ ys,
                       const unsigned short* __restrict__ csr,
                       const int* __restrict__ cnt,
                       const float* __restrict__ cc, const float* __restrict__ ns,
                       const float* __restrict__ nd,
                       const float* __restrict__ bb, const float* __restrict__ b3) {
    __shared__ unsigned short rows[4][4][64];   // [wave][node][entry] = 2 KB
    int wid  = threadIdx.x >> 6;
    int lane = threadIdx.x & 63;
    int q    = (blockIdx.x & 7) >> 1;
    int half = blockIdx.x & 1;
    int g    = (blockIdx.x >> 3) * 8 + wid * 2 + half;   // 4-node group id
    if (g >= NGROUPS) return;
    int node0 = g << 2;

    // stage 4 csr rows (4 x 128 B) into LDS
    int nn = lane >> 4, sl = lane & 15;
    const unsigned short* crow = csr + ((size_t)(node0 + nn) << 6) + sl;
    unsigned short r0 = crow[0], r1 = crow[16], r2 = crow[32], r3 = crow[48];
    unsigned short* myrow = &rows[wid][nn][0];
    myrow[sl] = r0; myrow[sl + 16] = r1; myrow[sl + 32] = r2; myrow[sl + 48] = r3;

    // wave-uniform loop bound: max degree of the 4 nodes (scalar loads)
    int n0u = __builtin_amdgcn_readfirstlane(node0);
    int m = cnt[n0u];
    int t1 = cnt[n0u + 1]; if (t1 > m) m = t1;
    int t2 = cnt[n0u + 2]; if (t2 > m) m = t2;
    int t3 = cnt[n0u + 3]; if (t3 > m) m = t3;
    m = (m + 7) & ~7;

    int n = lane >> 4, e = (lane >> 2) & 3, c4 = lane & 3;
    const unsigned short* rd = &rows[wid][n][e];        // entry (4t+e) at rd[4t]
    const float* xq = xs + (size_t)q * SLICE + (c4 << 2);

    float ax = 0.f, ay = 0.f, az = 0.f, aw = 0.f;
    for (int j = 0; j < m; j += 8) {                    // 8 edges per node per iter
        int s0 = rd[j];
        int s1 = rd[j + 4];
        const float4 t0v = *(const float4*)(xq + ((size_t)s0 << 4));
        const float4 t1v = *(const float4*)(xq + ((size_t)s1 << 4));
        ax += t0v.x; ay += t0v.y; az += t0v.z; aw += t0v.w;
        ax += t1v.x; ay += t1v.y; az += t1v.z; aw += t1v.w;
    }
    // reduce over edge-slots e (lane bits 2..3)
    ax += __shfl_xor(ax, 4);  ay += __shfl_xor(ay, 4);
    az += __shfl_xor(az, 4);  aw += __shfl_xor(aw, 4);
    ax += __shfl_xor(ax, 8);  ay += __shfl_xor(ay, 8);
    az += __shfl_xor(az, 8);  aw += __shfl_xor(aw, 8);

    int nodeL = node0 + n;
    int colq  = (q << 4) + (c4 << 2);
    float4 r;
    if (MODE == 0) {
        float cv = cc[nodeL], nv = ns[nodeL];
        float4 bv = *(const float4*)(bb + colq);
        r.x = cv * ax + nv * bv.x; r.y = cv * ay + nv * bv.y;
        r.z = cv * az + nv * bv.z; r.w = cv * aw + nv * bv.w;
    } else if (MODE == 1) {
        float cv = cc[nodeL];
        r.x = cv * ax; r.y = cv * ay; r.z = cv * az; r.w = cv * aw;
    } else {
        float dv = nd[nodeL];
        float4 bv = *(const float4*)(b3 + colq);
        r.x = dv * ax + bv.x; r.y = dv * ay + bv.y;
        r.z = dv * az + bv.z; r.w = dv * aw + bv.w;
    }
    if (e == 0) {
        if (MODE == 2)
            *(float4*)(ys + ((size_t)nodeL << 6) + colq) = r;
        else
            *(float4*)(ys + (size_t)q * SLICE + ((size_t)nodeL << 4) + (c4 << 2)) = r;
    }
}

// ---------------- launcher ----------------

extern "C" void kernel_launch(void* const* d_in, const int* in_sizes, int n_in,
                              void* d_out, int out_size, void* d_ws, size_t ws_size,
                              hipStream_t stream) {
    const float* X   = (const float*)d_in[0];
    const int*   src = (const int*)d_in[1];
    const int*   dst = (const int*)d_in[2];
    const float* W1  = (const float*)d_in[3];
    const float* b1  = (const float*)d_in[4];
    const float* W3  = (const float*)d_in[5];
    const float* b3  = (const float*)d_in[6];
    float* out = (float*)d_out;

    char* ws = (char*)d_ws;
    size_t off = 0;
    auto alloc = [&](size_t bytes) -> void* {
        void* p = ws + off;
        off = (off + bytes + 255) & ~(size_t)255;
        return p;
    };
    // big buffers, time-multiplexed (stream order guarantees safety):
    //   bufA: partialsS (hist src) -> prefix -> Y1 (sliced)
    //   bufB: partialsD (hist dst) -> Y0 (sliced)
    const size_t BIGSZ = SLICE * 4 * 4;   // 12.8 MB >= HBLOCKS*HWORDS*4
    char* bufA = (char*)alloc(BIGSZ);
    char* bufB = (char*)alloc(BIGSZ);
    int*            deg_in  = (int*)alloc((size_t)N_NODES * 4);
    unsigned short* csr     = (unsigned short*)alloc((size_t)N_NODES * CSTRIDE * 2);
    float*          ns      = (float*)alloc((size_t)N_NODES * 4);
    float*          nd      = (float*)alloc((size_t)N_NODES * 4);
    float*          cc      = (float*)alloc((size_t)N_NODES * 4);
    float*          W13     = (float*)alloc((size_t)DIN * DOUT * 4);
    float*          bb      = (float*)alloc(DOUT * 4);

    unsigned int* pS   = (unsigned int*)bufA;
    unsigned int* pD   = (unsigned int*)bufB;
    unsigned int* pref = (unsigned int*)bufA;
    float*        Y0   = (float*)bufB;
    float*        Y1   = (float*)bufA;

    const int hblk = (HWORDS + 255) / 256;    // 49
    const int sblk = 1563 * 8;                // 12504 blocks -> 12500 groups x 4 slices

    k_sent<<<(N_EDGES / 256), 256, 0, stream>>>((unsigned int*)csr);
    k_hist<<<HBLOCKS, 256, 0, stream>>>(src, pS);
    k_hist<<<HBLOCKS, 256, 0, stream>>>(dst, pD);
    k_hpre<<<hblk, 256, 0, stream>>>(pS, pD, pref, deg_in, ns, nd, cc);
    k_fill<<<HBLOCKS, 256, 0, stream>>>(src, dst, pref, csr);

    k_weights<<<66, 256, 0, stream>>>(W1, b1, W3, W13, bb, Y0, Y1);

    // Y0 = ns ∘ (X @ (W1@W3)), column-sliced
    k_gemm<<<(N_NODES + 63) / 64, 256, 0, stream>>>(X, W13, ns, Y0);

    // 6 propagation passes; bias bb injected in pass 1, b3 in pass 6
    k_spmm<0><<<sblk, 256, 0, stream>>>(Y0, Y1, csr, deg_in, cc, ns, nd, bb, b3);
    k_spmm<1><<<sblk, 256, 0, stream>>>(Y1, Y0, csr, deg_in, cc, ns, nd, bb, b3);
    k_spmm<1><<<sblk, 256, 0, stream>>>(Y0, Y1, csr, deg_in, cc, ns, nd, bb, b3);
    k_spmm<1><<<sblk, 256, 0, stream>>>(Y1, Y0, csr, deg_in, cc, ns, nd, bb, b3);
    k_spmm<1><<<sblk, 256, 0, stream>>>(Y0, Y1, csr, deg_in, cc, ns, nd, bb, b3);
    k_spmm<2><<<sblk, 256, 0, stream>>>(Y1, out, csr, deg_in, cc, ns, nd, bb, b3);
}

// Round 8
// 315.284 us; speedup vs baseline: 1.3341x; 1.0346x over previous
//
#include <hip/hip_runtime.h>
#include <math.h>

#define N_NODES 50000
#define N_EDGES 800000
#define DIN 256
#define DHID 128
#define DOUT 64
// Padded CSR row stride. In-degree ~ Poisson(16); P(deg > 64) ~ 1e-19 -> safe.
#define CSTRIDE 64
#define ZROW N_NODES            // sentinel row (kept zero)
#define HBLOCKS 256
#define HCHUNK (N_EDGES / HBLOCKS)     // 3125 exactly
#define HWORDS (N_NODES / 4)           // 12500 packed byte-counters per block
#define SLICE ((size_t)(N_NODES + 1) * 16)   // floats per 16-col slice
#define NGROUPS (N_NODES / 4)          // 12500 4-node groups
#define PBLOCKS 49                     // hpre/dscatter blocks (12500/256 rounded up)

// ---------------- fat setup kernel: sentinel-fill csr, 2 histograms, weight folds ----
#define SB_SENT 3125
#define SB_HS (SB_SENT + HBLOCKS)       // 3381
#define SB_HD (SB_HS + HBLOCKS)         // 3637
#define SB_TOT (SB_HD + 66)             // 3703

__global__ void k_setup(const int* __restrict__ src, const int* __restrict__ dst,
                        unsigned int* __restrict__ pS, unsigned int* __restrict__ pD,
                        unsigned int* __restrict__ csr32,
                        const float* __restrict__ W1, const float* __restrict__ b1,
                        const float* __restrict__ W3,
                        float* __restrict__ W13, float* __restrict__ bb,
                        float* __restrict__ Y0, float* __restrict__ Y1) {
    __shared__ unsigned int h[HWORDS];
    int bx = blockIdx.x, t = threadIdx.x;
    if (bx < SB_SENT) {
        // pre-fill every csr slot with the sentinel (k_fill overwrites [0,deg))
        unsigned int v = (unsigned int)ZROW | ((unsigned int)ZROW << 16);
        uint2 o; o.x = v; o.y = v;
        ((uint2*)csr32)[bx * 256 + t] = o;
        return;
    }
    if (bx < SB_HD) {
        // byte-packed LDS-privatized histogram (4 bins per u32); per-block
        // per-node counts <= total degree (<=64) << 255 -> no byte carry.
        const int* idx = (bx < SB_HS) ? src : dst;
        unsigned int* outp = (bx < SB_HS) ? pS : pD;
        int hb = bx - ((bx < SB_HS) ? SB_SENT : SB_HS);
        for (int w = t; w < HWORDS; w += 256) h[w] = 0u;
        __syncthreads();
        int base = hb * HCHUNK;
        for (int i = t; i < HCHUNK; i += 256) {
            int s = idx[base + i];
            atomicAdd(&h[s >> 2], 1u << ((s & 3) << 3));
        }
        __syncthreads();
        outp += (size_t)hb * HWORDS;
        for (int w = t; w < HWORDS; w += 256) outp[w] = h[w];
        return;
    }
    int vb = bx - SB_HD;                 // 0..65
    if (vb == 65) {
        if (t < 64) {                    // zero the sentinel row in both buffers
            int qq = t >> 4, c2 = t & 15;
            Y0[(size_t)qq * SLICE + ((size_t)ZROW << 4) + c2] = 0.f;
            Y1[(size_t)qq * SLICE + ((size_t)ZROW << 4) + c2] = 0.f;
        }
        return;
    }
    if (vb == 64) {
        if (t < DOUT) {
            float s = 0.f;
            for (int k = 0; k < DHID; ++k) s += b1[k] * W3[k * DOUT + t];
            bb[t] = s;
        }
        return;
    }
    int idx2 = vb * 256 + t;             // 16384 outputs of W13 = W1@W3
    int i = idx2 >> 6, j = idx2 & 63;
    float s = 0.f;
    for (int k = 0; k < DHID; ++k) s += W1[i * DHID + k] * W3[k * DOUT + j];
    W13[idx2] = s;
}

// ---------------- merged reduce/scan/norms + degree histogram ----------------
// deg_out = byte-sum(pS); prefix/deg_in = packed scan(pD); norms ns/nd/cc;
// per-block degree histogram (65 bins) for the counting sort.
__global__ void k_hpre(const unsigned int* __restrict__ pS,
                       const unsigned int* __restrict__ pD,
                       unsigned int* __restrict__ prefix,
                       int* __restrict__ deg_in,
                       float* __restrict__ ns, float* __restrict__ nd,
                       float* __restrict__ cc, int* __restrict__ dparts) {
    __shared__ int lh[65];
    int t = threadIdx.x;
    if (t < 65) lh[t] = 0;
    __syncthreads();
    int wid = blockIdx.x * 256 + t;
    if (wid < HWORDS) {
        unsigned int o0 = 0, o1 = 0, o2 = 0, o3 = 0;
#pragma unroll 4
        for (int b = 0; b < HBLOCKS; ++b) {
            unsigned int w = pS[(size_t)b * HWORDS + wid];
            o0 += w & 0xffu; o1 += (w >> 8) & 0xffu;
            o2 += (w >> 16) & 0xffu; o3 += w >> 24;
        }
        unsigned int run = 0;
        for (int b = 0; b < HBLOCKS; ++b) {
            unsigned int w = pD[(size_t)b * HWORDS + wid];
            prefix[(size_t)b * HWORDS + wid] = run;
            run += w;                    // packed per-byte add, no carry (deg<=64)
        }
        unsigned int i0 = run & 0xffu, i1 = (run >> 8) & 0xffu;
        unsigned int i2 = (run >> 16) & 0xffu, i3 = run >> 24;
        int4 di; di.x = (int)i0; di.y = (int)i1; di.z = (int)i2; di.w = (int)i3;
        *(int4*)(deg_in + (wid << 2)) = di;

        unsigned int dov[4] = {o0, o1, o2, o3};
        unsigned int div_[4] = {i0, i1, i2, i3};
        float4 vns, vnd, vcc;
        float* pns = &vns.x; float* pnd = &vnd.x; float* pcc = &vcc.x;
#pragma unroll
        for (int q = 0; q < 4; ++q) {
            int bin = (int)div_[q]; if (bin > 64) bin = 64;
            atomicAdd(&lh[bin], 1);
            unsigned int a = dov[q] < 1u ? 1u : dov[q];
            unsigned int b = div_[q] < 1u ? 1u : div_[q];
            float fa = 1.0f / sqrtf((float)a);
            float fb = 1.0f / sqrtf((float)b);
            pns[q] = fa; pnd[q] = fb; pcc[q] = fa * fb;
        }
        *(float4*)(ns + (wid << 2)) = vns;
        *(float4*)(nd + (wid << 2)) = vnd;
        *(float4*)(cc + (wid << 2)) = vcc;
    }
    __syncthreads();
    if (t < 65) dparts[blockIdx.x * 65 + t] = lh[t];
}

// ---------------- counting-sort scan: per-(block,bin) slot bases, DESCENDING degree ----
__global__ void k_dscan(const int* __restrict__ dparts, int* __restrict__ offs) {
    __shared__ int colsum[65], binbase[65];
    int t = threadIdx.x;
    if (t < 65) {
        int s = 0;
        for (int b = 0; b < PBLOCKS; ++b) s += dparts[b * 65 + t];
        colsum[t] = s;
    }
    __syncthreads();
    if (t == 0) {
        int run = 0;
        for (int k = 64; k >= 0; --k) { binbase[k] = run; run += colsum[k]; }
    }
    __syncthreads();
    if (t < 65) {
        int run = binbase[t];
        for (int b = 0; b < PBLOCKS; ++b) { offs[b * 65 + t] = run; run += dparts[b * 65 + t]; }
    }
}

// ---------------- scatter: build perm/inv + permuted degree & norm arrays ----------------
__global__ void k_dscatter(const int* __restrict__ deg_in, const int* __restrict__ offs,
                           const float* __restrict__ cc, const float* __restrict__ ns,
                           const float* __restrict__ nd,
                           int* __restrict__ perm, int* __restrict__ inv,
                           int* __restrict__ degP, float* __restrict__ ccP,
                           float* __restrict__ nsP, float* __restrict__ ndP) {
    __shared__ int off[65];
    int t = threadIdx.x;
    if (t < 65) off[t] = offs[blockIdx.x * 65 + t];
    __syncthreads();
    int wid = blockIdx.x * 256 + t;
    if (wid < HWORDS) {
        int4 d4 = *(const int4*)(deg_in + (wid << 2));
        int dd[4] = {d4.x, d4.y, d4.z, d4.w};
#pragma unroll
        for (int k = 0; k < 4; ++k) {
            int node = (wid << 2) + k;
            int bin = dd[k] > 64 ? 64 : dd[k];
            int slot = atomicAdd(&off[bin], 1);
            perm[slot] = node; inv[node] = slot;
            degP[slot] = dd[k];
            ccP[slot] = cc[node]; nsP[slot] = ns[node]; ndP[slot] = nd[node];
        }
    }
}

// ---------------- fill csr (renumbered space) using LDS atomics only ----------------
__global__ void k_fill(const int* __restrict__ src, const int* __restrict__ dst,
                       const unsigned int* __restrict__ prefix,
                       const int* __restrict__ inv,
                       unsigned short* __restrict__ csr) {
    __shared__ unsigned int h[HWORDS];
    int t = threadIdx.x;
    const unsigned int* prow = prefix + (size_t)blockIdx.x * HWORDS;
    for (int w = t; w < HWORDS; w += 256) h[w] = prow[w];
    __syncthreads();
    int base = blockIdx.x * HCHUNK;
    for (int i = t; i < HCHUNK; i += 256) {
        int s = src[base + i], d = dst[base + i];
        int sh = (d & 3) << 3;
        unsigned int old = atomicAdd(&h[d >> 2], 1u << sh);
        int slot = (int)((old >> sh) & 0xffu);
        csr[((size_t)inv[d] << 6) + slot] = (unsigned short)inv[s];
    }
}

// ---------------- dense GEMM: Y[inv[row]] = ns[row] ∘ (X @ W13), COLUMN-SLICED --------
__global__ void k_gemm(const float* __restrict__ X, const float* __restrict__ W13,
                       const float* __restrict__ ns, const int* __restrict__ inv,
                       float* __restrict__ Y) {
    __shared__ float As[16][68];
    __shared__ float Bs[16][64];
    int tid = threadIdx.x;
    int tx = tid & 15, ty = tid >> 4;
    int row0 = blockIdx.x * 64;
    float acc[4][4];
#pragma unroll
    for (int i = 0; i < 4; ++i)
#pragma unroll
        for (int j = 0; j < 4; ++j) acc[i][j] = 0.f;

    int lr = tid >> 2;
    int lk = (tid & 3) << 2;
    int arow = row0 + lr;
    if (arow > N_NODES - 1) arow = N_NODES - 1;   // clamp: garbage rows never stored

    for (int k0 = 0; k0 < DIN; k0 += 16) {
        float4 a = *(const float4*)(X + (size_t)arow * DIN + k0 + lk);
        As[lk + 0][lr] = a.x; As[lk + 1][lr] = a.y;
        As[lk + 2][lr] = a.z; As[lk + 3][lr] = a.w;
        float4 b = *(const float4*)(W13 + (size_t)(k0 + (tid >> 4)) * DOUT + ((tid & 15) << 2));
        *(float4*)&Bs[tid >> 4][(tid & 15) << 2] = b;
        __syncthreads();
#pragma unroll
        for (int k = 0; k < 16; ++k) {
            float4 av = *(const float4*)&As[k][ty << 2];
            float4 bv = *(const float4*)&Bs[k][tx << 2];
            float ar[4] = {av.x, av.y, av.z, av.w};
            float br[4] = {bv.x, bv.y, bv.z, bv.w};
#pragma unroll
            for (int i = 0; i < 4; ++i)
#pragma unroll
                for (int j = 0; j < 4; ++j) acc[i][j] += ar[i] * br[j];
        }
        __syncthreads();
    }
    int qq = tx >> 2;
    int co = (tx & 3) << 2;
#pragma unroll
    for (int i = 0; i < 4; ++i) {
        int row = row0 + (ty << 2) + i;
        if (row < N_NODES) {
            float nsr = ns[row];
            int prow = inv[row];
            float4 o;
            o.x = acc[i][0] * nsr; o.y = acc[i][1] * nsr;
            o.z = acc[i][2] * nsr; o.w = acc[i][3] * nsr;
            *(float4*)(Y + (size_t)qq * SLICE + ((size_t)prow << 4) + co) = o;
        }
    }
}

// ---------------- sliced pull SpMM, degree-sorted: 4 nodes x 4 edge-slots x float4 ------
// Nodes renumbered in descending-degree order -> groups of 4 have ~equal degree;
// loop bound m = pad8(degP[node0]) (first is group max). Wave-uniform m lets us
// branch to a fully unrolled path issuing all m/4 gathers back-to-back (<=8 in
// flight). Sentinel entries hit the zeroed ZROW row.
// MODE 0: y = cc*acc + ns*bb[col]; MODE 1: y = cc*acc;
// MODE 2: out[perm[node]] = nd*acc + b3[col]  (row-major, original numbering).

template <int MODE>
__launch_bounds__(256, 8)
__global__ void k_spmm(const float* __restrict__ xs, float* __restrict__ ys,
                       const unsigned short* __restrict__ csr,
                       const int* __restrict__ degP,
                       const float* __restrict__ ccP, const float* __restrict__ nsP,
                       const float* __restrict__ ndP,
                       const float* __restrict__ bb, const float* __restrict__ b3,
                       const int* __restrict__ perm) {
    __shared__ unsigned short rows[4][4][64];   // [wave][node][entry] = 2 KB
    int wid  = threadIdx.x >> 6;
    int lane = threadIdx.x & 63;
    int q    = (blockIdx.x & 7) >> 1;
    int half = blockIdx.x & 1;
    int g    = (blockIdx.x >> 3) * 8 + wid * 2 + half;   // 4-node group id
    if (g >= NGROUPS) return;
    int node0 = g << 2;

    // stage 4 csr rows (4 x 128 B) into LDS: one uint2 (4 entries) per lane
    int nn = lane >> 4, sl = lane & 15;
    const uint2* crow = (const uint2*)(csr + ((size_t)(node0 + nn) << 6)) + sl;
    uint2 rv = *crow;
    *(uint2*)(&rows[wid][nn][sl << 2]) = rv;

    int n0u = __builtin_amdgcn_readfirstlane(node0);
    int m = (degP[n0u] + 7) & ~7;        // group max (descending sort)

    int n = lane >> 4, e = (lane >> 2) & 3, c4 = lane & 3;
    const unsigned short* rd = &rows[wid][n][e];        // entry (4t+e) at rd[4t]
    const float* xq = xs + (size_t)q * SLICE + (c4 << 2);

    float ax = 0.f, ay = 0.f, az = 0.f, aw = 0.f;
#define LDV(T) const float4 v##T = *(const float4*)(xq + ((size_t)rd[4 * (T)] << 4))
#define ACCV(T) ax += v##T.x; ay += v##T.y; az += v##T.z; aw += v##T.w
    if (m <= 8) {
        LDV(0); LDV(1);
        ACCV(0); ACCV(1);
    } else if (m <= 16) {
        LDV(0); LDV(1); LDV(2); LDV(3);
        ACCV(0); ACCV(1); ACCV(2); ACCV(3);
    } else if (m <= 24) {
        LDV(0); LDV(1); LDV(2); LDV(3); LDV(4); LDV(5);
        ACCV(0); ACCV(1); ACCV(2); ACCV(3); ACCV(4); ACCV(5);
    } else if (m <= 32) {
        LDV(0); LDV(1); LDV(2); LDV(3); LDV(4); LDV(5); LDV(6); LDV(7);
        ACCV(0); ACCV(1); ACCV(2); ACCV(3); ACCV(4); ACCV(5); ACCV(6); ACCV(7);
    } else {
        for (int j = 0; j < m; j += 8) {
            const float4 a = *(const float4*)(xq + ((size_t)rd[j] << 4));
            const float4 b = *(const float4*)(xq + ((size_t)rd[j + 4] << 4));
            ax += a.x; ay += a.y; az += a.z; aw += a.w;
            ax += b.x; ay += b.y; az += b.z; aw += b.w;
        }
    }
#undef LDV
#undef ACCV
    // reduce over edge-slots e (lane bits 2..3)
    ax += __shfl_xor(ax, 4);  ay += __shfl_xor(ay, 4);
    az += __shfl_xor(az, 4);  aw += __shfl_xor(aw, 4);
    ax += __shfl_xor(ax, 8);  ay += __shfl_xor(ay, 8);
    az += __shfl_xor(az, 8);  aw += __shfl_xor(aw, 8);

    int nodeL = node0 + n;
    int colq  = (q << 4) + (c4 << 2);
    float4 r;
    if (MODE == 0) {
        float cv = ccP[nodeL], nv = nsP[nodeL];
        float4 bv = *(const float4*)(bb + colq);
        r.x = cv * ax + nv * bv.x; r.y = cv * ay + nv * bv.y;
        r.z = cv * az + nv * bv.z; r.w = cv * aw + nv * bv.w;
    } else if (MODE == 1) {
        float cv = ccP[nodeL];
        r.x = cv * ax; r.y = cv * ay; r.z = cv * az; r.w = cv * aw;
    } else {
        float dv = ndP[nodeL];
        float4 bv = *(const float4*)(b3 + colq);
        r.x = dv * ax + bv.x; r.y = dv * ay + bv.y;
        r.z = dv * az + bv.z; r.w = dv * aw + bv.w;
    }
    if (e == 0) {
        if (MODE == 2) {
            int orow = perm[nodeL];
            *(float4*)(ys + ((size_t)orow << 6) + colq) = r;
        } else {
            *(float4*)(ys + (size_t)q * SLICE + ((size_t)nodeL << 4) + (c4 << 2)) = r;
        }
    }
}

// ---------------- launcher ----------------

extern "C" void kernel_launch(void* const* d_in, const int* in_sizes, int n_in,
                              void* d_out, int out_size, void* d_ws, size_t ws_size,
                              hipStream_t stream) {
    const float* X   = (const float*)d_in[0];
    const int*   src = (const int*)d_in[1];
    const int*   dst = (const int*)d_in[2];
    const float* W1  = (const float*)d_in[3];
    const float* b1  = (const float*)d_in[4];
    const float* W3  = (const float*)d_in[5];
    const float* b3  = (const float*)d_in[6];
    float* out = (float*)d_out;

    char* ws = (char*)d_ws;
    size_t off = 0;
    auto alloc = [&](size_t bytes) -> void* {
        void* p = ws + off;
        off = (off + bytes + 255) & ~(size_t)255;
        return p;
    };
    // ws is ~256 MB (harness poison size) -> no aliasing needed (~75 MB used)
    unsigned int*   pS     = (unsigned int*)alloc((size_t)HBLOCKS * HWORDS * 4);  // 12.8 MB
    unsigned int*   pD     = (unsigned int*)alloc((size_t)HBLOCKS * HWORDS * 4);  // 12.8 MB
    unsigned int*   pref   = (unsigned int*)alloc((size_t)HBLOCKS * HWORDS * 4);  // 12.8 MB
    float*          Y0     = (float*)alloc(SLICE * 4 * 4);                        // 12.8 MB
    float*          Y1     = (float*)alloc(SLICE * 4 * 4);                        // 12.8 MB
    unsigned short* csr    = (unsigned short*)alloc((size_t)N_NODES * CSTRIDE * 2);
    int*            deg_in = (int*)alloc((size_t)N_NODES * 4);
    float*          ns     = (float*)alloc((size_t)N_NODES * 4);
    float*          nd     = (float*)alloc((size_t)N_NODES * 4);
    float*          cc     = (float*)alloc((size_t)N_NODES * 4);
    int*            perm   = (int*)alloc((size_t)N_NODES * 4);
    int*            inv    = (int*)alloc((size_t)N_NODES * 4);
    int*            degP   = (int*)alloc((size_t)N_NODES * 4);
    float*          ccP    = (float*)alloc((size_t)N_NODES * 4);
    float*          nsP    = (float*)alloc((size_t)N_NODES * 4);
    float*          ndP    = (float*)alloc((size_t)N_NODES * 4);
    int*            dparts = (int*)alloc((size_t)PBLOCKS * 65 * 4);
    int*            offs   = (int*)alloc((size_t)PBLOCKS * 65 * 4);
    float*          W13    = (float*)alloc((size_t)DIN * DOUT * 4);
    float*          bb     = (float*)alloc(DOUT * 4);

    const int sblk = 1563 * 8;   // 12504 blocks -> 12500 groups x 4 slices

    k_setup<<<SB_TOT, 256, 0, stream>>>(src, dst, pS, pD, (unsigned int*)csr,
                                        W1, b1, W3, W13, bb, Y0, Y1);
    k_hpre<<<PBLOCKS, 256, 0, stream>>>(pS, pD, pref, deg_in, ns, nd, cc, dparts);
    k_dscan<<<1, 256, 0, stream>>>(dparts, offs);
    k_dscatter<<<PBLOCKS, 256, 0, stream>>>(deg_in, offs, cc, ns, nd,
                                            perm, inv, degP, ccP, nsP, ndP);
    k_fill<<<HBLOCKS, 256, 0, stream>>>(src, dst, pref, inv, csr);

    // Y0 = ns ∘ (X @ (W1@W3)), column-sliced, renumbered rows
    k_gemm<<<(N_NODES + 63) / 64, 256, 0, stream>>>(X, W13, ns, inv, Y0);

    // 6 propagation passes; bias bb injected in pass 1, b3 in pass 6
    k_spmm<0><<<sblk, 256, 0, stream>>>(Y0, Y1, csr, degP, ccP, nsP, ndP, bb, b3, perm);
    k_spmm<1><<<sblk, 256, 0, stream>>>(Y1, Y0, csr, degP, ccP, nsP, ndP, bb, b3, perm);
    k_spmm<1><<<sblk, 256, 0, stream>>>(Y0, Y1, csr, degP, ccP, nsP, ndP, bb, b3, perm);
    k_spmm<1><<<sblk, 256, 0, stream>>>(Y1, Y0, csr, degP, ccP, nsP, ndP, bb, b3, perm);
    k_spmm<1><<<sblk, 256, 0, stream>>>(Y0, Y1, csr, degP, ccP, nsP, ndP, bb, b3, perm);
    k_spmm<2><<<sblk, 256, 0, stream>>>(Y1, out, csr, degP, ccP, nsP, ndP, bb, b3, perm);
}

// Round 10
// 305.262 us; speedup vs baseline: 1.3779x; 1.0328x over previous
//
#include <hip/hip_runtime.h>
#include <math.h>

#define N_NODES 50000
#define N_EDGES 800000
#define DIN 256
#define DHID 128
#define DOUT 64
// Padded CSR row stride. In-degree ~ Poisson(16); P(deg > 64) ~ 1e-19 -> safe.
#define CSTRIDE 64
#define ZROW N_NODES            // sentinel row (kept zero)
#define HBLOCKS 256
#define HCHUNK (N_EDGES / HBLOCKS)     // 3125
#define HWORDS (N_NODES / 4)           // 12500
#define SLICE ((size_t)(N_NODES + 1) * 16)
#define NGROUPS (N_NODES / 4)          // 12500
#define P2BLOCKS 196                   // hpre/dscatter blocks (12500/64 word-cols)

// ---------------- fat setup kernel: sentinel-fill csr, 2 histograms, weight folds ----
#define SB_SENT 3125
#define SB_HS (SB_SENT + HBLOCKS)       // 3381
#define SB_HD (SB_HS + HBLOCKS)         // 3637
#define SB_TOT (SB_HD + 66)             // 3703

__global__ void k_setup(const int* __restrict__ src, const int* __restrict__ dst,
                        unsigned int* __restrict__ pS, unsigned int* __restrict__ pD,
                        unsigned int* __restrict__ csr32,
                        const float* __restrict__ W1, const float* __restrict__ b1,
                        const float* __restrict__ W3,
                        float* __restrict__ W13, float* __restrict__ bb,
                        float* __restrict__ Y0, float* __restrict__ Y1) {
    __shared__ unsigned int h[HWORDS];
    int bx = blockIdx.x, t = threadIdx.x;
    if (bx < SB_SENT) {
        // pre-fill every csr slot with the sentinel (k_fill overwrites [0,deg))
        unsigned int v = (unsigned int)ZROW | ((unsigned int)ZROW << 16);
        uint2 o; o.x = v; o.y = v;
        ((uint2*)csr32)[bx * 256 + t] = o;
        return;
    }
    if (bx < SB_HD) {
        // byte-packed LDS-privatized histogram (4 bins per u32); per-block
        // per-node counts <= total degree (<=64) << 255 -> no byte carry.
        const int* idx = (bx < SB_HS) ? src : dst;
        unsigned int* outp = (bx < SB_HS) ? pS : pD;
        int hb = bx - ((bx < SB_HS) ? SB_SENT : SB_HS);
        for (int w = t; w < HWORDS; w += 256) h[w] = 0u;
        __syncthreads();
        int base = hb * HCHUNK;
        for (int i = t; i < HCHUNK; i += 256) {
            int s = idx[base + i];
            atomicAdd(&h[s >> 2], 1u << ((s & 3) << 3));
        }
        __syncthreads();
        outp += (size_t)hb * HWORDS;
        for (int w = t; w < HWORDS; w += 256) outp[w] = h[w];
        return;
    }
    int vb = bx - SB_HD;                 // 0..65
    if (vb == 65) {
        if (t < 64) {                    // zero the sentinel row in both buffers
            int qq = t >> 4, c2 = t & 15;
            Y0[(size_t)qq * SLICE + ((size_t)ZROW << 4) + c2] = 0.f;
            Y1[(size_t)qq * SLICE + ((size_t)ZROW << 4) + c2] = 0.f;
        }
        return;
    }
    if (vb == 64) {
        if (t < DOUT) {
            float s = 0.f;
            for (int k = 0; k < DHID; ++k) s += b1[k] * W3[k * DOUT + t];
            bb[t] = s;
        }
        return;
    }
    int idx2 = vb * 256 + t;             // 16384 outputs of W13 = W1@W3
    int i = idx2 >> 6, j = idx2 & 63;
    float s = 0.f;
    for (int k = 0; k < DHID; ++k) s += W1[i * DHID + k] * W3[k * DOUT + j];
    W13[idx2] = s;
}

// ---------------- hpre: 4-way-parallel scan + reduce + norms + degree hist ----------------
// thread = (col, sub): col = t>>2 owns packed word wid, sub = t&3 scans 64 of
// the 256 hist blocks. Packed byte sums never carry (per-node totals <= 64).
__global__ void k_hpre(const unsigned int* __restrict__ pS,
                       const unsigned int* __restrict__ pD,
                       unsigned int* __restrict__ prefix,
                       int* __restrict__ deg_in,
                       float* __restrict__ ns, float* __restrict__ nd,
                       float* __restrict__ cc, int* __restrict__ dparts) {
    __shared__ unsigned int sdw[64][4];
    __shared__ unsigned int sow[64][4];
    __shared__ int lh[65];
    int t = threadIdx.x;
    if (t < 65) lh[t] = 0;
    int col = t >> 2, sub = t & 3;
    int wid = blockIdx.x * 64 + col;
    bool act = wid < HWORDS;
    unsigned int ps = 0, pd = 0;
    if (act) {
        int b0 = sub << 6;
#pragma unroll 4
        for (int b = b0; b < b0 + 64; ++b) {
            ps += pS[(size_t)b * HWORDS + wid];
            pd += pD[(size_t)b * HWORDS + wid];
        }
    }
    sdw[col][sub] = pd;
    sow[col][sub] = ps;
    __syncthreads();
    if (act) {
        unsigned int base = 0;
        for (int k = 0; k < sub; ++k) base += sdw[col][k];
        int b0 = sub << 6;
        unsigned int run = base;
        for (int b = b0; b < b0 + 64; ++b) {
            unsigned int w = pD[(size_t)b * HWORDS + wid];
            prefix[(size_t)b * HWORDS + wid] = run;
            run += w;
        }
        if (sub == 0) {
            unsigned int totd = sdw[col][0] + sdw[col][1] + sdw[col][2] + sdw[col][3];
            unsigned int toto = sow[col][0] + sow[col][1] + sow[col][2] + sow[col][3];
            unsigned int di[4] = {totd & 0xffu, (totd >> 8) & 0xffu,
                                  (totd >> 16) & 0xffu, totd >> 24};
            unsigned int dov[4] = {toto & 0xffu, (toto >> 8) & 0xffu,
                                   (toto >> 16) & 0xffu, toto >> 24};
            int4 dd; dd.x = (int)di[0]; dd.y = (int)di[1]; dd.z = (int)di[2]; dd.w = (int)di[3];
            *(int4*)(deg_in + (wid << 2)) = dd;
            float4 vns, vnd, vcc;
            float* pns = &vns.x; float* pnd = &vnd.x; float* pcc = &vcc.x;
#pragma unroll
            for (int q = 0; q < 4; ++q) {
                int bin = (int)di[q]; if (bin > 64) bin = 64;
                atomicAdd(&lh[bin], 1);
                unsigned int a = dov[q] < 1u ? 1u : dov[q];
                unsigned int b = di[q] < 1u ? 1u : di[q];
                float fa = 1.0f / sqrtf((float)a);
                float fb = 1.0f / sqrtf((float)b);
                pns[q] = fa; pnd[q] = fb; pcc[q] = fa * fb;
            }
            *(float4*)(ns + (wid << 2)) = vns;
            *(float4*)(nd + (wid << 2)) = vnd;
            *(float4*)(cc + (wid << 2)) = vcc;
        }
    }
    __syncthreads();
    if (t < 65) dparts[blockIdx.x * 65 + t] = lh[t];
}

// ---------------- counting-sort scan (DESCENDING degree) ----------------
__global__ void k_dscan(const int* __restrict__ dparts, int* __restrict__ offs) {
    __shared__ int colsum[65], binbase[65];
    int t = threadIdx.x;
    if (t < 65) {
        int s = 0;
        for (int b = 0; b < P2BLOCKS; ++b) s += dparts[b * 65 + t];
        colsum[t] = s;
    }
    __syncthreads();
    if (t == 0) {
        int run = 0;
        for (int k = 64; k >= 0; --k) { binbase[k] = run; run += colsum[k]; }
    }
    __syncthreads();
    if (t < 65) {
        int run = binbase[t];
        for (int b = 0; b < P2BLOCKS; ++b) { offs[b * 65 + t] = run; run += dparts[b * 65 + t]; }
    }
}

// ---------------- scatter: perm/inv + permuted degree & norm arrays ----------------
__global__ void k_dscatter(const int* __restrict__ deg_in, const int* __restrict__ offs,
                           const float* __restrict__ cc, const float* __restrict__ ns,
                           const float* __restrict__ nd,
                           int* __restrict__ perm, int* __restrict__ inv,
                           int* __restrict__ degP, float* __restrict__ ccP,
                           float* __restrict__ nsP, float* __restrict__ ndP) {
    __shared__ int off[65];
    int t = threadIdx.x;
    if (t < 65) off[t] = offs[blockIdx.x * 65 + t];
    __syncthreads();
    int wid = blockIdx.x * 64 + t;
    if (t < 64 && wid < HWORDS) {
        int4 d4 = *(const int4*)(deg_in + (wid << 2));
        int dd[4] = {d4.x, d4.y, d4.z, d4.w};
#pragma unroll
        for (int k = 0; k < 4; ++k) {
            int node = (wid << 2) + k;
            int bin = dd[k] > 64 ? 64 : dd[k];
            int slot = atomicAdd(&off[bin], 1);
            perm[slot] = node; inv[node] = slot;
            degP[slot] = dd[k];
            ccP[slot] = cc[node]; nsP[slot] = ns[node]; ndP[slot] = nd[node];
        }
    }
}

// ---------------- fill csr (renumbered space) using LDS atomics only ----------------
__global__ void k_fill(const int* __restrict__ src, const int* __restrict__ dst,
                       const unsigned int* __restrict__ prefix,
                       const int* __restrict__ inv,
                       unsigned short* __restrict__ csr) {
    __shared__ unsigned int h[HWORDS];
    int t = threadIdx.x;
    const unsigned int* prow = prefix + (size_t)blockIdx.x * HWORDS;
    for (int w = t; w < HWORDS; w += 256) h[w] = prow[w];
    __syncthreads();
    int base = blockIdx.x * HCHUNK;
    for (int i = t; i < HCHUNK; i += 256) {
        int s = src[base + i], d = dst[base + i];
        int sh = (d & 3) << 3;
        unsigned int old = atomicAdd(&h[d >> 2], 1u << sh);
        int slot = (int)((old >> sh) & 0xffu);
        csr[((size_t)inv[d] << 6) + slot] = (unsigned short)inv[s];
    }
}

// ---------------- dense GEMM: Y[inv[row]] = ns[row] ∘ (X @ W13), COLUMN-SLICED --------
__global__ void k_gemm(const float* __restrict__ X, const float* __restrict__ W13,
                       const float* __restrict__ ns, const int* __restrict__ inv,
                       float* __restrict__ Y) {
    __shared__ float As[16][68];
    __shared__ float Bs[16][64];
    int tid = threadIdx.x;
    int tx = tid & 15, ty = tid >> 4;
    int row0 = blockIdx.x * 64;
    float acc[4][4];
#pragma unroll
    for (int i = 0; i < 4; ++i)
#pragma unroll
        for (int j = 0; j < 4; ++j) acc[i][j] = 0.f;

    int lr = tid >> 2;
    int lk = (tid & 3) << 2;
    int arow = row0 + lr;
    if (arow > N_NODES - 1) arow = N_NODES - 1;   // clamp: garbage rows never stored

    for (int k0 = 0; k0 < DIN; k0 += 16) {
        float4 a = *(const float4*)(X + (size_t)arow * DIN + k0 + lk);
        As[lk + 0][lr] = a.x; As[lk + 1][lr] = a.y;
        As[lk + 2][lr] = a.z; As[lk + 3][lr] = a.w;
        float4 b = *(const float4*)(W13 + (size_t)(k0 + (tid >> 4)) * DOUT + ((tid & 15) << 2));
        *(float4*)&Bs[tid >> 4][(tid & 15) << 2] = b;
        __syncthreads();
#pragma unroll
        for (int k = 0; k < 16; ++k) {
            float4 av = *(const float4*)&As[k][ty << 2];
            float4 bv = *(const float4*)&Bs[k][tx << 2];
            float ar[4] = {av.x, av.y, av.z, av.w};
            float br[4] = {bv.x, bv.y, bv.z, bv.w};
#pragma unroll
            for (int i = 0; i < 4; ++i)
#pragma unroll
                for (int j = 0; j < 4; ++j) acc[i][j] += ar[i] * br[j];
        }
        __syncthreads();
    }
    int qq = tx >> 2;
    int co = (tx & 3) << 2;
#pragma unroll
    for (int i = 0; i < 4; ++i) {
        int row = row0 + (ty << 2) + i;
        if (row < N_NODES) {
            float nsr = ns[row];
            int prow = inv[row];
            float4 o;
            o.x = acc[i][0] * nsr; o.y = acc[i][1] * nsr;
            o.z = acc[i][2] * nsr; o.w = acc[i][3] * nsr;
            *(float4*)(Y + (size_t)qq * SLICE + ((size_t)prow << 4) + co) = o;
        }
    }
}

// ---------------- sliced pull SpMM, degree-sorted: 4 nodes x 4 edge-slots x float4 ------
// Nodes renumbered in descending-degree order -> groups of 4 have ~equal degree;
// loop bound m = pad8(degP[node0]) (first is group max). Wave-uniform m branches
// to a fully unrolled path issuing all m/4 gathers back-to-back (<=8 in flight).
// LDS rows stored TRANSPOSED [entry*4 + node]: hot-loop ds_read_u16 addresses
// (4e+n)/2 + 8T hit 8 distinct banks -> conflict-free (old [node][entry] layout
// collapsed 8 addresses onto 2 banks = 4-way conflict, ~1.58x per m136).
// MODE 0: y = cc*acc + ns*bb[col]; MODE 1: y = cc*acc;
// MODE 2: out[perm[node]] = nd*acc + b3[col]  (row-major, original numbering).

template <int MODE>
__launch_bounds__(256, 8)
__global__ void k_spmm(const float* __restrict__ xs, float* __restrict__ ys,
                       const unsigned short* __restrict__ csr,
                       const int* __restrict__ degP,
                       const float* __restrict__ ccP, const float* __restrict__ nsP,
                       const float* __restrict__ ndP,
                       const float* __restrict__ bb, const float* __restrict__ b3,
                       const int* __restrict__ perm) {
    __shared__ unsigned short rows[4][256];     // [wave][entry*4 + node] = 2 KB
    int wid  = threadIdx.x >> 6;
    int lane = threadIdx.x & 63;
    int q    = (blockIdx.x & 7) >> 1;
    int half = blockIdx.x & 1;
    int g    = (blockIdx.x >> 3) * 8 + wid * 2 + half;   // 4-node group id
    if (g >= NGROUPS) return;
    int node0 = g << 2;

    // stage 4 csr rows (4 x 128 B) into LDS, transposed: lane (nn,sl) loads
    // entries 4sl..4sl+3 of node nn and writes them at [(4sl+k)*4 + nn].
    int nn = lane >> 4, sl = lane & 15;
    const uint2* crow = (const uint2*)(csr + ((size_t)(node0 + nn) << 6)) + sl;
    uint2 rv = *crow;
    unsigned short* bp = &rows[wid][(sl << 4) + nn];
    bp[0]  = (unsigned short)(rv.x & 0xffffu);
    bp[4]  = (unsigned short)(rv.x >> 16);
    bp[8]  = (unsigned short)(rv.y & 0xffffu);
    bp[12] = (unsigned short)(rv.y >> 16);

    int n0u = __builtin_amdgcn_readfirstlane(node0);
    int m = (degP[n0u] + 7) & ~7;        // group max (descending sort)

    int n = lane >> 4, e = (lane >> 2) & 3, c4 = lane & 3;
    const unsigned short* rd = &rows[wid][(e << 2) + n];   // entry (e+4T) at rd[16T]
    const float* xq = xs + (size_t)q * SLICE + (c4 << 2);

    float ax = 0.f, ay = 0.f, az = 0.f, aw = 0.f;
#define LDV(T) const float4 v##T = *(const float4*)(xq + ((size_t)rd[16 * (T)] << 4))
#define ACCV(T) ax += v##T.x; ay += v##T.y; az += v##T.z; aw += v##T.w
    if (m <= 8) {
        LDV(0); LDV(1);
        ACCV(0); ACCV(1);
    } else if (m <= 16) {
        LDV(0); LDV(1); LDV(2); LDV(3);
        ACCV(0); ACCV(1); ACCV(2); ACCV(3);
    } else if (m <= 24) {
        LDV(0); LDV(1); LDV(2); LDV(3); LDV(4); LDV(5);
        ACCV(0); ACCV(1); ACCV(2); ACCV(3); ACCV(4); ACCV(5);
    } else if (m <= 32) {
        LDV(0); LDV(1); LDV(2); LDV(3); LDV(4); LDV(5); LDV(6); LDV(7);
        ACCV(0); ACCV(1); ACCV(2); ACCV(3); ACCV(4); ACCV(5); ACCV(6); ACCV(7);
    } else {
        for (int j2 = 0; j2 < m; j2 += 8) {
            int o = j2 << 2;
            const float4 a = *(const float4*)(xq + ((size_t)rd[o] << 4));
            const float4 b = *(const float4*)(xq + ((size_t)rd[o + 16] << 4));
            ax += a.x; ay += a.y; az += a.z; aw += a.w;
            ax += b.x; ay += b.y; az += b.z; aw += b.w;
        }
    }
#undef LDV
#undef ACCV
    // reduce over edge-slots e (lane bits 2..3)
    ax += __shfl_xor(ax, 4);  ay += __shfl_xor(ay, 4);
    az += __shfl_xor(az, 4);  aw += __shfl_xor(aw, 4);
    ax += __shfl_xor(ax, 8);  ay += __shfl_xor(ay, 8);
    az += __shfl_xor(az, 8);  aw += __shfl_xor(aw, 8);

    int nodeL = node0 + n;
    int colq  = (q << 4) + (c4 << 2);
    float4 r;
    if (MODE == 0) {
        float cv = ccP[nodeL], nv = nsP[nodeL];
        float4 bv = *(const float4*)(bb + colq);
        r.x = cv * ax + nv * bv.x; r.y = cv * ay + nv * bv.y;
        r.z = cv * az + nv * bv.z; r.w = cv * aw + nv * bv.w;
    } else if (MODE == 1) {
        float cv = ccP[nodeL];
        r.x = cv * ax; r.y = cv * ay; r.z = cv * az; r.w = cv * aw;
    } else {
        float dv = ndP[nodeL];
        float4 bv = *(const float4*)(b3 + colq);
        r.x = dv * ax + bv.x; r.y = dv * ay + bv.y;
        r.z = dv * az + bv.z; r.w = dv * aw + bv.w;
    }
    if (e == 0) {
        if (MODE == 2) {
            int orow = perm[nodeL];
            *(float4*)(ys + ((size_t)orow << 6) + colq) = r;
        } else {
            *(float4*)(ys + (size_t)q * SLICE + ((size_t)nodeL << 4) + (c4 << 2)) = r;
        }
    }
}

// ---------------- launcher ----------------

extern "C" void kernel_launch(void* const* d_in, const int* in_sizes, int n_in,
                              void* d_out, int out_size, void* d_ws, size_t ws_size,
                              hipStream_t stream) {
    const float* X   = (const float*)d_in[0];
    const int*   src = (const int*)d_in[1];
    const int*   dst = (const int*)d_in[2];
    const float* W1  = (const float*)d_in[3];
    const float* b1  = (const float*)d_in[4];
    const float* W3  = (const float*)d_in[5];
    const float* b3  = (const float*)d_in[6];
    float* out = (float*)d_out;

    char* ws = (char*)d_ws;
    size_t off = 0;
    auto alloc = [&](size_t bytes) -> void* {
        void* p = ws + off;
        off = (off + bytes + 255) & ~(size_t)255;
        return p;
    };
    unsigned int*   pS     = (unsigned int*)alloc((size_t)HBLOCKS * HWORDS * 4);
    unsigned int*   pD     = (unsigned int*)alloc((size_t)HBLOCKS * HWORDS * 4);
    unsigned int*   pref   = (unsigned int*)alloc((size_t)HBLOCKS * HWORDS * 4);
    float*          Y0     = (float*)alloc(SLICE * 4 * 4);
    float*          Y1     = (float*)alloc(SLICE * 4 * 4);
    unsigned short* csr    = (unsigned short*)alloc((size_t)N_NODES * CSTRIDE * 2);
    int*            deg_in = (int*)alloc((size_t)N_NODES * 4);
    float*          ns     = (float*)alloc((size_t)N_NODES * 4);
    float*          nd     = (float*)alloc((size_t)N_NODES * 4);
    float*          cc     = (float*)alloc((size_t)N_NODES * 4);
    int*            perm   = (int*)alloc((size_t)N_NODES * 4);
    int*            inv    = (int*)alloc((size_t)N_NODES * 4);
    int*            degP   = (int*)alloc((size_t)N_NODES * 4);
    float*          ccP    = (float*)alloc((size_t)N_NODES * 4);
    float*          nsP    = (float*)alloc((size_t)N_NODES * 4);
    float*          ndP    = (float*)alloc((size_t)N_NODES * 4);
    int*            dparts = (int*)alloc((size_t)P2BLOCKS * 65 * 4);
    int*            offs   = (int*)alloc((size_t)P2BLOCKS * 65 * 4);
    float*          W13    = (float*)alloc((size_t)DIN * DOUT * 4);
    float*          bb     = (float*)alloc(DOUT * 4);

    const int sblk = 1563 * 8;   // 12504 blocks -> 12500 groups x 4 slices

    k_setup<<<SB_TOT, 256, 0, stream>>>(src, dst, pS, pD, (unsigned int*)csr,
                                        W1, b1, W3, W13, bb, Y0, Y1);
    k_hpre<<<P2BLOCKS, 256, 0, stream>>>(pS, pD, pref, deg_in, ns, nd, cc, dparts);
    k_dscan<<<1, 128, 0, stream>>>(dparts, offs);
    k_dscatter<<<P2BLOCKS, 128, 0, stream>>>(deg_in, offs, cc, ns, nd,
                                             perm, inv, degP, ccP, nsP, ndP);
    k_fill<<<HBLOCKS, 256, 0, stream>>>(src, dst, pref, inv, csr);

    // Y0 = ns ∘ (X @ (W1@W3)), column-sliced, renumbered rows
    k_gemm<<<(N_NODES + 63) / 64, 256, 0, stream>>>(X, W13, ns, inv, Y0);

    // 6 propagation passes; bias bb injected in pass 1, b3 in pass 6
    k_spmm<0><<<sblk, 256, 0, stream>>>(Y0, Y1, csr, degP, ccP, nsP, ndP, bb, b3, perm);
    k_spmm<1><<<sblk, 256, 0, stream>>>(Y1, Y0, csr, degP, ccP, nsP, ndP, bb, b3, perm);
    k_spmm<1><<<sblk, 256, 0, stream>>>(Y0, Y1, csr, degP, ccP, nsP, ndP, bb, b3, perm);
    k_spmm<1><<<sblk, 256, 0, stream>>>(Y1, Y0, csr, degP, ccP, nsP, ndP, bb, b3, perm);
    k_spmm<1><<<sblk, 256, 0, stream>>>(Y0, Y1, csr, degP, ccP, nsP, ndP, bb, b3, perm);
    k_spmm<2><<<sblk, 256, 0, stream>>>(Y1, out, csr, degP, ccP, nsP, ndP, bb, b3, perm);
}